// Round 3
// baseline (308.714 us; speedup 1.0000x reference)
//
#include <hip/hip_runtime.h>
#include <hip/hip_bf16.h>

// Problem constants
#define B_ROWS 32768
#define LN_EPS 1e-5f
// GEMM2 N = 320: 256 (Z) + 25 (yt via folded C) + 39 zero pad
// GEMM2 K = 544: 512 (H') + 16 (ut*dt) + 1 (const) + 15 pad; kk2 in [0,17)

typedef __bf16 bf16;
using bf16x8 = __attribute__((ext_vector_type(8))) __bf16;
using f32x4  = __attribute__((ext_vector_type(4))) float;

// ---------------- workspace layout (bytes) ----------------
// W1sw [32G][10kk][4q][16m][8e] bf16 : 327,680 @ 0
// Psw  [20G][17kk][4q][16m][8e] bf16 : 348,160 @ 327,680
// Mtmp [4,64,128] f32               : 131,072 @ 675,840
// cvec [256] f32                    :   1,024 @ 806,912
// CW   [25,4,64] f32                :  25,600 @ 807,936
// total ~0.8 MB

// exact-GELU via A&S 7.1.26 rational erf (|eps| <= 1.5e-7), branch-free
__device__ __forceinline__ float gelu_exact(float x) {
  float s = x * 0.70710678118f;
  float a = fabsf(s);
  float t = __builtin_amdgcn_rcpf(fmaf(0.3275911f, a, 1.0f));
  float p = fmaf(fmaf(fmaf(fmaf(1.061405429f, t, -1.453152027f),
                           t, 1.421413741f), t, -0.284496736f), t, 0.254829592f) * t;
  float e = __expf(-s * s);
  float er = fmaf(-p, e, 1.0f);
  er = copysignf(er, s);
  return 0.5f * x * (1.0f + er);
}

// ---------------- prep 1: W1sw (gate-folded, fragment-swizzled layout),
// Mtmp = BmatG*W2, cvec = BmatG*b2, CW[o,n,r] = sum_d C[o,d]*Wout[n,d,r]
__global__ __launch_bounds__(256) void prep_weights1(
    const float* __restrict__ gates, const float* __restrict__ W1,
    const float* __restrict__ Bmat,  const float* __restrict__ W2,
    const float* __restrict__ b2,    const float* __restrict__ Wout,
    const float* __restrict__ Cm,
    bf16* __restrict__ W1sw, float* __restrict__ Mtmp, float* __restrict__ cvec,
    float* __restrict__ CW)
{
  const int stride = gridDim.x * blockDim.x;
  const int id = blockIdx.x * blockDim.x + threadIdx.x;
  // output-major over swizzled layout: o = ((G*10+kk)*4+q)*128 + m*8 + e
  for (int o = id; o < 512 * 320; o += stride) {
    int e = o & 7, m = (o >> 3) & 15, q2 = (o >> 7) & 3, rest = o >> 9;
    int kk = rest % 10, G = rest / 10;
    int n = G * 16 + m, k = kk * 32 + q2 * 8 + e;
    float wv = W1[n * 320 + k];
    if (k < 256) {
      float g = gates[(n >> 7) * 256 + k];
      wv *= 1.f / (1.f + __expf(-g));
    }
    W1sw[o] = (bf16)wv;
  }
  for (int i = id; i < 4 * 64 * 128; i += stride) {
    int n = i >> 13, r = (i >> 7) & 63, h = i & 127;
    float s = 0.f;
    for (int j = 0; j < 64; ++j)
      s += Bmat[(n * 64 + r) * 80 + j] * W2[(n * 64 + j) * 128 + h];
    Mtmp[i] = s;
  }
  for (int i = id; i < 256; i += stride) {
    int n = i >> 6, r = i & 63;
    float s = 0.f;
    for (int j = 0; j < 64; ++j)
      s += Bmat[(n * 64 + r) * 80 + j] * b2[n * 64 + j];
    cvec[i] = s;
  }
  for (int i = id; i < 25 * 256; i += stride) {
    int o = i >> 8, nr = i & 255;
    float s = 0.f;
    for (int d = 0; d < 256; ++d)
      s += Cm[o * 256 + d] * Wout[((nr >> 6) * 256 + d) * 64 + (nr & 63)];
    CW[i] = s;
  }
}

// ---------------- prep 2: Psw fragment-swizzled [320 rows][544 cols]
// rows 0..255 (d): [P | Q | czn | 0]; rows 256..280 (o): [C*P | C*Q + D | C*czn | 0];
// rows 281..319: 0
__global__ __launch_bounds__(256) void prep_weights2(
    const float* __restrict__ Wout, const float* __restrict__ Bmat,
    const float* __restrict__ Mtmp, const float* __restrict__ cvec,
    const float* __restrict__ CW,   const float* __restrict__ Dm,
    bf16* __restrict__ Psw)
{
  const int stride = gridDim.x * blockDim.x;
  const int id = blockIdx.x * blockDim.x + threadIdx.x;
  for (int o = id; o < 320 * 544; o += stride) {
    int e = o & 7, m = (o >> 3) & 15, q2 = (o >> 7) & 3, rest = o >> 9;
    int kk2 = rest % 17, G2 = rest / 17;
    int dd = G2 * 16 + m, cc = kk2 * 32 + q2 * 8 + e;
    float s = 0.f;
    if (dd < 281) {
      const bool isC = (dd >= 256);
      const int oo = dd - 256;
      if (cc < 512) {
        int n = cc >> 7, h = cc & 127;
        for (int r = 0; r < 64; ++r) {
          float wv = isC ? CW[(oo * 4 + n) * 64 + r] : Wout[(n * 256 + dd) * 64 + r];
          s += wv * Mtmp[(n * 64 + r) * 128 + h];
        }
      } else if (cc < 528) {
        int u = cc - 512;
        for (int n = 0; n < 4; ++n)
          for (int r = 0; r < 64; ++r) {
            float wv = isC ? CW[(oo * 4 + n) * 64 + r] : Wout[(n * 256 + dd) * 64 + r];
            s += wv * Bmat[(n * 64 + r) * 80 + 64 + u];
          }
        if (isC) s += Dm[oo * 16 + u];
      } else if (cc == 528) {
        for (int n = 0; n < 4; ++n)
          for (int r = 0; r < 64; ++r) {
            float wv = isC ? CW[(oo * 4 + n) * 64 + r] : Wout[(n * 256 + dd) * 64 + r];
            s += wv * cvec[n * 64 + r];
          }
      }
    }
    Psw[o] = (bf16)s;
  }
}

// ---------------- fused: per 128-row block:
//   for each branch c: H_c = GELU(LN(X*W1^T+b1)) in LDS  ->  Z += H_c * P_c^T
// B operands read straight from global (pre-swizzled, L2-resident) — K-loops
// are barrier-free; barriers only bracket the LN tile (16 per block).
__global__ __launch_bounds__(512, 2) void fused_main(
    const float* __restrict__ zdyn, const float* __restrict__ zst,
    const float* __restrict__ ut,   const float* __restrict__ dtp,
    const bf16* __restrict__ W1sw,  const bf16* __restrict__ Psw,
    const float* __restrict__ b1,   const float* __restrict__ gamma,
    const float* __restrict__ beta,
    float* __restrict__ Z, float* __restrict__ yt)
{
  __shared__ __align__(16) bf16 Hc[4 * 128 * 32];   // 32 KB: current branch H tile
  __shared__ __align__(16) bf16 Ht[128 * 32];       //  8 KB: [ut*dt | 1 | 0] K-tail
  __shared__ float sgam[512], sbet[512], sb1[512];  //  6 KB
  __shared__ float smu[128], srs[128];              //  1 KB

  const int t = threadIdx.x;
  const int lane = t & 63, m16 = lane & 15, q = lane >> 4;
  const int w = t >> 6, wrow = (w & 1) * 64, wcol = w >> 1;
  const int rowBase = blockIdx.x * 128;

  sgam[t] = gamma[t]; sbet[t] = beta[t]; sb1[t] = b1[t];

  {
    const float dtv = dtp[0];
    int r = t >> 2, pq = t & 3;
    int lq = pq ^ ((r >> 1) & 3);
    bf16x8 o;
    #pragma unroll
    for (int e = 0; e < 8; ++e) {
      int ci = lq * 8 + e;
      float v = (ci < 16) ? ut[(size_t)(rowBase + r) * 16 + ci] * dtv
                          : (ci == 16 ? 1.f : 0.f);
      o[e] = (bf16)v;
    }
    *(bf16x8*)&Ht[t * 8] = o;
  }

  f32x4 accZ[4][5];
  #pragma unroll
  for (int i = 0; i < 4; ++i)
    #pragma unroll
    for (int j = 0; j < 5; ++j)
      #pragma unroll
      for (int r = 0; r < 4; ++r) accZ[i][j][r] = 0.f;

  #pragma unroll 1
  for (int c = 0; c < 4; ++c) {
    // ---- phase 1: acc1 = X * W1eff_c^T  (barrier-free K-loop) ----
    f32x4 acc1[4][2];
    #pragma unroll
    for (int i = 0; i < 4; ++i)
      #pragma unroll
      for (int j = 0; j < 2; ++j)
        #pragma unroll
        for (int r = 0; r < 4; ++r) acc1[i][j][r] = 0.f;

    #pragma unroll
    for (int kk = 0; kk < 10; ++kk) {
      bf16x8 bfr[2];
      #pragma unroll
      for (int j = 0; j < 2; ++j) {
        int G = c * 8 + wcol * 2 + j;
        bfr[j] = *(const bf16x8*)&W1sw[(size_t)(((G * 10 + kk) * 4 + q) * 16 + m16) * 8];
      }
      bf16x8 af[4];
      #pragma unroll
      for (int i = 0; i < 4; ++i) {
        int row = rowBase + wrow + i * 16 + m16;
        const float* src = (kk < 8) ? &zdyn[(size_t)row * 256 + kk * 32 + q * 8]
                                    : &zst[(size_t)row * 64 + (kk - 8) * 32 + q * 8];
        float4 v0 = *(const float4*)src;
        float4 v1 = *(const float4*)(src + 4);
        af[i][0] = (bf16)v0.x; af[i][1] = (bf16)v0.y;
        af[i][2] = (bf16)v0.z; af[i][3] = (bf16)v0.w;
        af[i][4] = (bf16)v1.x; af[i][5] = (bf16)v1.y;
        af[i][6] = (bf16)v1.z; af[i][7] = (bf16)v1.w;
      }
      #pragma unroll
      for (int i = 0; i < 4; ++i)
        #pragma unroll
        for (int j = 0; j < 2; ++j)
          acc1[i][j] = __builtin_amdgcn_mfma_f32_16x16x32_bf16(af[i], bfr[j], acc1[i][j], 0, 0, 0);
    }

    // ---- LN tile: write pre-LN H (+b1) to LDS ----
    __syncthreads();   // protect Hc from previous branch's phase-2 readers
    #pragma unroll
    for (int j = 0; j < 2; ++j) {
      int tc = j * 16 + m16;
      float bb = sb1[c * 128 + wcol * 32 + tc];
      int lq2 = tc >> 3, e2 = tc & 7;
      #pragma unroll
      for (int i = 0; i < 4; ++i)
        #pragma unroll
        for (int rr = 0; rr < 4; ++rr) {
          int row = wrow + i * 16 + q * 4 + rr;
          Hc[((wcol * 128 + row) * 4 + (lq2 ^ ((row >> 1) & 3))) * 8 + e2] =
              (bf16)(acc1[i][j][rr] + bb);
        }
    }
    __syncthreads();
    if (t < 128) {
      float s = 0.f, s2 = 0.f;
      #pragma unroll
      for (int tk = 0; tk < 4; ++tk)
        #pragma unroll
        for (int ch = 0; ch < 4; ++ch) {
          bf16x8 hv = *(const bf16x8*)&Hc[((tk * 128 + t) * 4 + ch) * 8];
          #pragma unroll
          for (int e = 0; e < 8; ++e) { float v = (float)hv[e]; s += v; s2 = fmaf(v, v, s2); }
        }
      float mu = s * 0.0078125f;
      float var = s2 * 0.0078125f - mu * mu;
      smu[t] = mu;
      srs[t] = rsqrtf(fmaxf(var, 0.f) + LN_EPS);
    }
    __syncthreads();
    #pragma unroll
    for (int a = 0; a < 4; ++a) {
      int id = t + 512 * a;
      int tk = id >> 9, rem = id & 511, r = rem >> 2, pq = rem & 3;
      int lq = pq ^ ((r >> 1) & 3);
      int gcol = c * 128 + tk * 32 + lq * 8;
      bf16x8 hv = *(const bf16x8*)&Hc[id * 8];
      float mu = smu[r], rs = srs[r];
      bf16x8 ov;
      #pragma unroll
      for (int e = 0; e < 8; ++e) {
        float v = ((float)hv[e] - mu) * rs;
        v = fmaf(v, sgam[gcol + e], sbet[gcol + e]);
        ov[e] = (bf16)gelu_exact(v);
      }
      *(bf16x8*)&Hc[id * 8] = ov;
    }
    __syncthreads();

    // ---- phase 2: Z += H_c * P_c^T  (barrier-free K-loop) ----
    #pragma unroll
    for (int tk = 0; tk < 4; ++tk) {
      int kk2 = c * 4 + tk;
      bf16x8 af[4], bfr[5];
      #pragma unroll
      for (int i = 0; i < 4; ++i) {
        int row = wrow + i * 16 + m16;
        af[i] = *(const bf16x8*)&Hc[((tk * 128 + row) * 4 + (q ^ ((row >> 1) & 3))) * 8];
      }
      #pragma unroll
      for (int j = 0; j < 5; ++j) {
        int G2 = wcol * 5 + j;
        bfr[j] = *(const bf16x8*)&Psw[(size_t)(((G2 * 17 + kk2) * 4 + q) * 16 + m16) * 8];
      }
      #pragma unroll
      for (int i = 0; i < 4; ++i)
        #pragma unroll
        for (int j = 0; j < 5; ++j)
          accZ[i][j] = __builtin_amdgcn_mfma_f32_16x16x32_bf16(af[i], bfr[j], accZ[i][j], 0, 0, 0);
    }
  }

  // ---- K tail (kk2 = 16): A = [ut*dt | 1 | 0] from Ht ----
  {
    bf16x8 af[4], bfr[5];
    #pragma unroll
    for (int i = 0; i < 4; ++i) {
      int row = wrow + i * 16 + m16;
      af[i] = *(const bf16x8*)&Ht[(row * 4 + (q ^ ((row >> 1) & 3))) * 8];
    }
    #pragma unroll
    for (int j = 0; j < 5; ++j) {
      int G2 = wcol * 5 + j;
      bfr[j] = *(const bf16x8*)&Psw[(size_t)(((G2 * 17 + 16) * 4 + q) * 16 + m16) * 8];
    }
    #pragma unroll
    for (int i = 0; i < 4; ++i)
      #pragma unroll
      for (int j = 0; j < 5; ++j)
        accZ[i][j] = __builtin_amdgcn_mfma_f32_16x16x32_bf16(af[i], bfr[j], accZ[i][j], 0, 0, 0);
  }

  // ---- store Z / yt ----
  #pragma unroll
  for (int i = 0; i < 4; ++i)
    #pragma unroll
    for (int j = 0; j < 5; ++j) {
      int col = wcol * 80 + j * 16 + m16;
      #pragma unroll
      for (int rr = 0; rr < 4; ++rr) {
        int row = rowBase + wrow + i * 16 + q * 4 + rr;
        if (col < 256) Z[(size_t)row * 256 + col] = accZ[i][j][rr];
        else if (col < 281) yt[(size_t)row * 25 + (col - 256)] = accZ[i][j][rr];
      }
    }
}

extern "C" void kernel_launch(void* const* d_in, const int* in_sizes, int n_in,
                              void* d_out, int out_size, void* d_ws, size_t ws_size,
                              hipStream_t stream) {
  const float* zdyn  = (const float*)d_in[0];
  const float* zst   = (const float*)d_in[1];
  const float* dtp   = (const float*)d_in[2];
  const float* ut    = (const float*)d_in[3];
  const float* gates = (const float*)d_in[4];
  const float* W1    = (const float*)d_in[5];
  const float* b1    = (const float*)d_in[6];
  const float* gamma = (const float*)d_in[7];
  const float* beta  = (const float*)d_in[8];
  const float* W2    = (const float*)d_in[9];
  const float* b2    = (const float*)d_in[10];
  // d_in[11], d_in[12] (lam_real/lam_imag) dead: h0 = 0
  const float* Bmat  = (const float*)d_in[13];
  const float* Wout  = (const float*)d_in[14];
  const float* Cm    = (const float*)d_in[15];
  const float* Dm    = (const float*)d_in[16];

  char* ws = (char*)d_ws;
  bf16*  W1sw = (bf16*)(ws);
  bf16*  Psw  = (bf16*)(ws + 327680);
  float* Mtmp = (float*)(ws + 675840);
  float* cvec = (float*)(ws + 806912);
  float* CW   = (float*)(ws + 807936);

  float* Z  = (float*)d_out;
  float* yt = Z + (size_t)B_ROWS * 256;

  hipLaunchKernelGGL(prep_weights1, dim3(128), dim3(256), 0, stream,
                     gates, W1, Bmat, W2, b2, Wout, Cm, W1sw, Mtmp, cvec, CW);
  hipLaunchKernelGGL(prep_weights2, dim3(256), dim3(256), 0, stream,
                     Wout, Bmat, Mtmp, cvec, CW, Dm, Psw);
  hipLaunchKernelGGL(fused_main, dim3(256), dim3(512), 0, stream,
                     zdyn, zst, ut, dtp, W1sw, Psw, b1, gamma, beta, Z, yt);
}

// Round 4
// 183.603 us; speedup vs baseline: 1.6814x; 1.6814x over previous
//
#include <hip/hip_runtime.h>
#include <hip/hip_bf16.h>

// Problem constants
#define B_ROWS 32768
#define LN_EPS 1e-5f
// GEMM2 N = 320: 256 (Z) + 25 (yt via folded C) + 39 zero pad
// GEMM2 K = 544: 512 (H') + 16 (ut*dt) + 1 (const) + 15 pad; kk2 in [0,17)

typedef __bf16 bf16;
using bf16x8 = __attribute__((ext_vector_type(8))) __bf16;
using f32x4  = __attribute__((ext_vector_type(4))) float;

// ---------------- workspace layout (bytes) ----------------
// W1sw [32G][10kk][4q][16m][8e] bf16 : 327,680 @ 0
// Psw  [20G][17kk][4q][16m][8e] bf16 : 348,160 @ 327,680
// Mtmp [4,64,128] f32               : 131,072 @ 675,840
// cvec [256] f32                    :   1,024 @ 806,912
// CW   [25,4,64] f32                :  25,600 @ 807,936
// total ~0.8 MB (keep ws small: harness re-poison of d_ws is timed)

// exact-GELU via A&S 7.1.26 rational erf (|eps| <= 1.5e-7), branch-free
__device__ __forceinline__ float gelu_exact(float x) {
  float s = x * 0.70710678118f;
  float a = fabsf(s);
  float t = __builtin_amdgcn_rcpf(fmaf(0.3275911f, a, 1.0f));
  float p = fmaf(fmaf(fmaf(fmaf(1.061405429f, t, -1.453152027f),
                           t, 1.421413741f), t, -0.284496736f), t, 0.254829592f) * t;
  float e = __expf(-s * s);
  float er = fmaf(-p, e, 1.0f);
  er = copysignf(er, s);
  return 0.5f * x * (1.0f + er);
}

// ---------------- prep 1: W1sw (gate-folded, fragment-swizzled layout),
// Mtmp = BmatG*W2, cvec = BmatG*b2, CW[o,n,r] = sum_d C[o,d]*Wout[n,d,r]
__global__ __launch_bounds__(256) void prep_weights1(
    const float* __restrict__ gates, const float* __restrict__ W1,
    const float* __restrict__ Bmat,  const float* __restrict__ W2,
    const float* __restrict__ b2,    const float* __restrict__ Wout,
    const float* __restrict__ Cm,
    bf16* __restrict__ W1sw, float* __restrict__ Mtmp, float* __restrict__ cvec,
    float* __restrict__ CW)
{
  const int stride = gridDim.x * blockDim.x;
  const int id = blockIdx.x * blockDim.x + threadIdx.x;
  // swizzled layout: o = ((G*10+kk)*4+q)*128 + m*8 + e ; n = G*16+m, k = kk*32+q*8+e
  for (int o = id; o < 512 * 320; o += stride) {
    int e = o & 7, m = (o >> 3) & 15, q2 = (o >> 7) & 3, rest = o >> 9;
    int kk = rest % 10, G = rest / 10;
    int n = G * 16 + m, k = kk * 32 + q2 * 8 + e;
    float wv = W1[n * 320 + k];
    if (k < 256) {
      float g = gates[(n >> 7) * 256 + k];
      wv *= 1.f / (1.f + __expf(-g));
    }
    W1sw[o] = (bf16)wv;
  }
  for (int i = id; i < 4 * 64 * 128; i += stride) {
    int n = i >> 13, r = (i >> 7) & 63, h = i & 127;
    float s = 0.f;
    for (int j = 0; j < 64; ++j)
      s += Bmat[(n * 64 + r) * 80 + j] * W2[(n * 64 + j) * 128 + h];
    Mtmp[i] = s;
  }
  for (int i = id; i < 256; i += stride) {
    int n = i >> 6, r = i & 63;
    float s = 0.f;
    for (int j = 0; j < 64; ++j)
      s += Bmat[(n * 64 + r) * 80 + j] * b2[n * 64 + j];
    cvec[i] = s;
  }
  for (int i = id; i < 25 * 256; i += stride) {
    int o = i >> 8, nr = i & 255;
    float s = 0.f;
    for (int d = 0; d < 256; ++d)
      s += Cm[o * 256 + d] * Wout[((nr >> 6) * 256 + d) * 64 + (nr & 63)];
    CW[i] = s;
  }
}

// ---------------- prep 2: Psw fragment-swizzled [320 rows][544 cols]
// rows 0..255 (d): [P | Q | czn | 0]; rows 256..280 (o): [C*P | C*Q + D | C*czn | 0];
// rows 281..319: 0
__global__ __launch_bounds__(256) void prep_weights2(
    const float* __restrict__ Wout, const float* __restrict__ Bmat,
    const float* __restrict__ Mtmp, const float* __restrict__ cvec,
    const float* __restrict__ CW,   const float* __restrict__ Dm,
    bf16* __restrict__ Psw)
{
  const int stride = gridDim.x * blockDim.x;
  const int id = blockIdx.x * blockDim.x + threadIdx.x;
  for (int o = id; o < 320 * 544; o += stride) {
    int e = o & 7, m = (o >> 3) & 15, q2 = (o >> 7) & 3, rest = o >> 9;
    int kk2 = rest % 17, G2 = rest / 17;
    int dd = G2 * 16 + m, cc = kk2 * 32 + q2 * 8 + e;
    float s = 0.f;
    if (dd < 281) {
      const bool isC = (dd >= 256);
      const int oo = dd - 256;
      if (cc < 512) {
        int n = cc >> 7, h = cc & 127;
        for (int r = 0; r < 64; ++r) {
          float wv = isC ? CW[(oo * 4 + n) * 64 + r] : Wout[(n * 256 + dd) * 64 + r];
          s += wv * Mtmp[(n * 64 + r) * 128 + h];
        }
      } else if (cc < 528) {
        int u = cc - 512;
        for (int n = 0; n < 4; ++n)
          for (int r = 0; r < 64; ++r) {
            float wv = isC ? CW[(oo * 4 + n) * 64 + r] : Wout[(n * 256 + dd) * 64 + r];
            s += wv * Bmat[(n * 64 + r) * 80 + 64 + u];
          }
        if (isC) s += Dm[oo * 16 + u];
      } else if (cc == 528) {
        for (int n = 0; n < 4; ++n)
          for (int r = 0; r < 64; ++r) {
            float wv = isC ? CW[(oo * 4 + n) * 64 + r] : Wout[(n * 256 + dd) * 64 + r];
            s += wv * cvec[n * 64 + r];
          }
      }
    }
    Psw[o] = (bf16)s;
  }
}

// ---------------- fused main: per 64-row block
//   stage X (bf16, swizzled) once -> for each branch c:
//     acc1 = X*W1_c^T (barrier-free, A from LDS, B frags from L2)
//     LN+GELU tile in LDS -> Z/yt accZ += H_c * P_c^T (barrier-free)
// 256 threads, 2 blocks/CU (LDS ~68 KB).
__global__ __launch_bounds__(256, 2) void fused_main(
    const float* __restrict__ zdyn, const float* __restrict__ zst,
    const float* __restrict__ ut,   const float* __restrict__ dtp,
    const bf16* __restrict__ W1sw,  const bf16* __restrict__ Psw,
    const float* __restrict__ b1,   const float* __restrict__ gamma,
    const float* __restrict__ beta,
    float* __restrict__ Z, float* __restrict__ yt)
{
  __shared__ __align__(16) bf16 Xs[64 * 320];       // 40 KB: X tile, swizzled A-layout
  __shared__ __align__(16) bf16 Hc[64 * 128];       //  8 KB pages x2 -> 16 KB
  __shared__ __align__(16) bf16 Ht[64 * 32];        //  4 KB: [ut*dt | 1 | 0] K-tail
  __shared__ float sgam[512], sbet[512], sb1[512];  //  6 KB
  __shared__ float red[256], red2[256];             //  2 KB
  __shared__ float smu[64], srs[64];                //  0.5 KB

  const int t = threadIdx.x;
  const int lane = t & 63, m16 = lane & 15, q = lane >> 4;
  const int w = t >> 6;
  const int rowBase = blockIdx.x * 64;

  sgam[t] = gamma[t]; sbet[t] = beta[t]; sb1[t] = b1[t];
  sgam[t + 256] = gamma[t + 256]; sbet[t + 256] = beta[t + 256]; sb1[t + 256] = b1[t + 256];

  // ---- stage X: 64 rows x 320 cols f32 -> bf16 swizzled: 2560 chunks of 8
  #pragma unroll
  for (int a = 0; a < 10; ++a) {
    int g = a * 256 + t;
    int row = g / 40, pos = g - row * 40;
    int kk = pos >> 2, pq = pos & 3;
    int lq = pq ^ ((row >> 1) & 3);
    int col = kk * 32 + lq * 8;
    const float* src = (col < 256) ? &zdyn[(size_t)(rowBase + row) * 256 + col]
                                   : &zst[(size_t)(rowBase + row) * 64 + (col - 256)];
    float4 v0 = *(const float4*)src;
    float4 v1 = *(const float4*)(src + 4);
    bf16x8 o;
    o[0]=(bf16)v0.x; o[1]=(bf16)v0.y; o[2]=(bf16)v0.z; o[3]=(bf16)v0.w;
    o[4]=(bf16)v1.x; o[5]=(bf16)v1.y; o[6]=(bf16)v1.z; o[7]=(bf16)v1.w;
    *(bf16x8*)&Xs[(size_t)((kk * 64 + row) * 4 + pq) * 8] = o;
  }
  // ---- stage Ht: [ut*dt | 1 | 0]
  {
    const float dtv = dtp[0];
    int r = t >> 2, pq = t & 3;
    int lq = pq ^ ((r >> 1) & 3);
    bf16x8 o;
    #pragma unroll
    for (int e = 0; e < 8; ++e) {
      int ci = lq * 8 + e;
      float v = (ci < 16) ? ut[(size_t)(rowBase + r) * 16 + ci] * dtv
                          : (ci == 16 ? 1.f : 0.f);
      o[e] = (bf16)v;
    }
    *(bf16x8*)&Ht[t * 8] = o;
  }
  __syncthreads();

  f32x4 accZ[4][5];
  #pragma unroll
  for (int i = 0; i < 4; ++i)
    #pragma unroll
    for (int j = 0; j < 5; ++j)
      #pragma unroll
      for (int r = 0; r < 4; ++r) accZ[i][j][r] = 0.f;

  #pragma unroll 1
  for (int c = 0; c < 4; ++c) {
    // ---- phase 1: acc1 = X * W1eff_c^T  (barrier-free K-loop) ----
    f32x4 acc1[4][2];
    #pragma unroll
    for (int i = 0; i < 4; ++i)
      #pragma unroll
      for (int j = 0; j < 2; ++j)
        #pragma unroll
        for (int r = 0; r < 4; ++r) acc1[i][j][r] = 0.f;

    #pragma unroll
    for (int kk = 0; kk < 10; ++kk) {
      bf16x8 bfr[2];
      #pragma unroll
      for (int j = 0; j < 2; ++j) {
        int G = c * 8 + w * 2 + j;
        bfr[j] = *(const bf16x8*)&W1sw[(size_t)(((G * 10 + kk) * 4 + q) * 16 + m16) * 8];
      }
      bf16x8 af[4];
      #pragma unroll
      for (int i = 0; i < 4; ++i) {
        int row = i * 16 + m16;
        af[i] = *(const bf16x8*)&Xs[(size_t)((kk * 64 + row) * 4 + (q ^ ((row >> 1) & 3))) * 8];
      }
      #pragma unroll
      for (int i = 0; i < 4; ++i)
        #pragma unroll
        for (int j = 0; j < 2; ++j)
          acc1[i][j] = __builtin_amdgcn_mfma_f32_16x16x32_bf16(af[i], bfr[j], acc1[i][j], 0, 0, 0);
    }

    // ---- LN tile: write pre-LN H (+b1) to Hc ----
    __syncthreads();   // all waves done reading Hc (prev branch phase 2)
    #pragma unroll
    for (int j = 0; j < 2; ++j) {
      int tc = w * 32 + j * 16 + m16;            // col within branch, 0..127
      float bb = sb1[c * 128 + tc];
      int tk = tc >> 5, ci = tc & 31;
      int lq2 = ci >> 3, e2 = ci & 7;
      #pragma unroll
      for (int i = 0; i < 4; ++i)
        #pragma unroll
        for (int rr = 0; rr < 4; ++rr) {
          int row = i * 16 + q * 4 + rr;
          Hc[((tk * 64 + row) * 4 + (lq2 ^ ((row >> 1) & 3))) * 8 + e2] =
              (bf16)(acc1[i][j][rr] + bb);
        }
    }
    __syncthreads();
    // ---- LN stats: partial over tk chunk per thread ----
    {
      int row = t >> 2, tk = t & 3;
      float s = 0.f, s2 = 0.f;
      #pragma unroll
      for (int ch = 0; ch < 4; ++ch) {
        bf16x8 hv = *(const bf16x8*)&Hc[((tk * 64 + row) * 4 + ch) * 8];
        #pragma unroll
        for (int e = 0; e < 8; ++e) { float v = (float)hv[e]; s += v; s2 = fmaf(v, v, s2); }
      }
      red[t] = s; red2[t] = s2;
    }
    __syncthreads();
    if (t < 64) {
      float ss = red[t * 4] + red[t * 4 + 1] + red[t * 4 + 2] + red[t * 4 + 3];
      float qq = red2[t * 4] + red2[t * 4 + 1] + red2[t * 4 + 2] + red2[t * 4 + 3];
      float mu = ss * 0.0078125f;
      float var = qq * 0.0078125f - mu * mu;
      smu[t] = mu;
      srs[t] = rsqrtf(fmaxf(var, 0.f) + LN_EPS);
    }
    __syncthreads();
    // ---- apply LN + GELU in place ----
    #pragma unroll
    for (int a = 0; a < 4; ++a) {
      int id = a * 256 + t;                       // 1024 chunks
      int pq = id & 3, row = (id >> 2) & 63, tk = id >> 8;
      int lq = pq ^ ((row >> 1) & 3);
      int gcol = c * 128 + tk * 32 + lq * 8;
      bf16x8 hv = *(const bf16x8*)&Hc[id * 8];
      float mu = smu[row], rs = srs[row];
      bf16x8 ov;
      #pragma unroll
      for (int e = 0; e < 8; ++e) {
        float v = ((float)hv[e] - mu) * rs;
        v = fmaf(v, sgam[gcol + e], sbet[gcol + e]);
        ov[e] = (bf16)gelu_exact(v);
      }
      *(bf16x8*)&Hc[id * 8] = ov;
    }
    __syncthreads();

    // ---- phase 2: accZ += H_c * P_c^T  (barrier-free K-loop) ----
    #pragma unroll
    for (int tk = 0; tk < 4; ++tk) {
      int kk2 = c * 4 + tk;
      bf16x8 af[4], bfr[5];
      #pragma unroll
      for (int i = 0; i < 4; ++i) {
        int row = i * 16 + m16;
        af[i] = *(const bf16x8*)&Hc[((tk * 64 + row) * 4 + (q ^ ((row >> 1) & 3))) * 8];
      }
      #pragma unroll
      for (int j = 0; j < 5; ++j) {
        int G2 = w * 5 + j;
        bfr[j] = *(const bf16x8*)&Psw[(size_t)(((G2 * 17 + kk2) * 4 + q) * 16 + m16) * 8];
      }
      #pragma unroll
      for (int i = 0; i < 4; ++i)
        #pragma unroll
        for (int j = 0; j < 5; ++j)
          accZ[i][j] = __builtin_amdgcn_mfma_f32_16x16x32_bf16(af[i], bfr[j], accZ[i][j], 0, 0, 0);
    }
  }

  // ---- K tail (kk2 = 16): A = [ut*dt | 1 | 0] from Ht ----
  {
    bf16x8 af[4], bfr[5];
    #pragma unroll
    for (int i = 0; i < 4; ++i) {
      int row = i * 16 + m16;
      af[i] = *(const bf16x8*)&Ht[(row * 4 + (q ^ ((row >> 1) & 3))) * 8];
    }
    #pragma unroll
    for (int j = 0; j < 5; ++j) {
      int G2 = w * 5 + j;
      bfr[j] = *(const bf16x8*)&Psw[(size_t)(((G2 * 17 + 16) * 4 + q) * 16 + m16) * 8];
    }
    #pragma unroll
    for (int i = 0; i < 4; ++i)
      #pragma unroll
      for (int j = 0; j < 5; ++j)
        accZ[i][j] = __builtin_amdgcn_mfma_f32_16x16x32_bf16(af[i], bfr[j], accZ[i][j], 0, 0, 0);
  }

  // ---- store Z / yt ----
  #pragma unroll
  for (int i = 0; i < 4; ++i)
    #pragma unroll
    for (int j = 0; j < 5; ++j) {
      int col = w * 80 + j * 16 + m16;
      #pragma unroll
      for (int rr = 0; rr < 4; ++rr) {
        int row = rowBase + i * 16 + q * 4 + rr;
        if (col < 256) Z[(size_t)row * 256 + col] = accZ[i][j][rr];
        else if (col < 281) yt[(size_t)row * 25 + (col - 256)] = accZ[i][j][rr];
      }
    }
}

extern "C" void kernel_launch(void* const* d_in, const int* in_sizes, int n_in,
                              void* d_out, int out_size, void* d_ws, size_t ws_size,
                              hipStream_t stream) {
  const float* zdyn  = (const float*)d_in[0];
  const float* zst   = (const float*)d_in[1];
  const float* dtp   = (const float*)d_in[2];
  const float* ut    = (const float*)d_in[3];
  const float* gates = (const float*)d_in[4];
  const float* W1    = (const float*)d_in[5];
  const float* b1    = (const float*)d_in[6];
  const float* gamma = (const float*)d_in[7];
  const float* beta  = (const float*)d_in[8];
  const float* W2    = (const float*)d_in[9];
  const float* b2    = (const float*)d_in[10];
  // d_in[11], d_in[12] (lam_real/lam_imag) dead: h0 = 0
  const float* Bmat  = (const float*)d_in[13];
  const float* Wout  = (const float*)d_in[14];
  const float* Cm    = (const float*)d_in[15];
  const float* Dm    = (const float*)d_in[16];

  char* ws = (char*)d_ws;
  bf16*  W1sw = (bf16*)(ws);
  bf16*  Psw  = (bf16*)(ws + 327680);
  float* Mtmp = (float*)(ws + 675840);
  float* cvec = (float*)(ws + 806912);
  float* CW   = (float*)(ws + 807936);

  float* Z  = (float*)d_out;
  float* yt = Z + (size_t)B_ROWS * 256;

  hipLaunchKernelGGL(prep_weights1, dim3(128), dim3(256), 0, stream,
                     gates, W1, Bmat, W2, b2, Wout, Cm, W1sw, Mtmp, cvec, CW);
  hipLaunchKernelGGL(prep_weights2, dim3(256), dim3(256), 0, stream,
                     Wout, Bmat, Mtmp, cvec, CW, Dm, Psw);
  hipLaunchKernelGGL(fused_main, dim3(512), dim3(256), 0, stream,
                     zdyn, zst, ut, dtp, W1sw, Psw, b1, gamma, beta, Z, yt);
}